// Round 7
// baseline (201.540 us; speedup 1.0000x reference)
//
#include <hip/hip_runtime.h>

#define BATCH 2048
#define DIM   256

typedef _Float16 half8 __attribute__((ext_vector_type(8)));  // 8 x f16 (4 VGPR)
typedef __attribute__((ext_vector_type(4))) float f32x4;

// Packed-weight tile table (layers 1..5):
// (FI,FO): (32,64) (64,128) (128,64) (64,32) (32,16)
// KT=FI/32, NT=FO/16, tiles=KT*NT: 4, 16, 16, 4, 1 -> bases 0,4,20,36,40
#define NTILES 41
#define TILE_HALVES 1024   // 64 lanes * 8 f16 * (hi+lo) = 2 KB

__device__ __forceinline__ void cvt8(const float* f, half8& h) {
#pragma unroll
  for (int j = 0; j < 8; ++j) h[j] = (_Float16)f[j];
}

// ---- prep: gather W into B-frag order, split f16 hi/lo. One block per
// (d, layer) -> 1280 independent blocks, no LDS, no barriers. ----
template <int FI, int FO, int BASE>
__device__ __forceinline__ void prep_layer(const float* __restrict__ W, int d,
                                           int t, _Float16* __restrict__ pack) {
  constexpr int KT = FI / 32, NT = FO / 16, T = KT * NT;
  const float* Wd = W + (size_t)d * FI * FO;
  for (int job = t; job < T * 64; job += 256) {
    const int tile = job >> 6, lane = job & 63;
    const int m = lane & 15, q = lane >> 4;
    const int nt = tile / KT, kt = tile % KT;   // matches main's nt*KT+kt
    const float* Wp = Wd + (size_t)(kt * 32 + q * 8) * FO + nt * 16 + m;
    half8 hi, lo;
#pragma unroll
    for (int j = 0; j < 8; ++j) {
      const float w = Wp[(size_t)j * FO];
      const _Float16 h = (_Float16)w;
      hi[j] = h;
      lo[j] = (_Float16)(w - (float)h);
    }
    _Float16* base = pack + (size_t)(d * NTILES + BASE + tile) * TILE_HALVES;
    *(half8*)(base + lane * 8) = hi;
    *(half8*)(base + 512 + lane * 8) = lo;
  }
}

__global__ __launch_bounds__(256) void prep_kernel(
    const float* __restrict__ W1, const float* __restrict__ W2,
    const float* __restrict__ W3, const float* __restrict__ W4,
    const float* __restrict__ W5, _Float16* __restrict__ pack) {
  const int d = blockIdx.x, t = threadIdx.x;
  switch (blockIdx.y) {
    case 0: prep_layer<32, 64, 0>(W1, d, t, pack); break;
    case 1: prep_layer<64, 128, 4>(W2, d, t, pack); break;
    case 2: prep_layer<128, 64, 20>(W3, d, t, pack); break;
    case 3: prep_layer<64, 32, 36>(W4, d, t, pack); break;
    default: prep_layer<32, 16, 40>(W5, d, t, pack); break;
  }
}

// ---- one MFMA layer for RT=4 row-tiles (M=64) owned by one wave ----
// A = f16 activations (hi only), B = f16 hi+lo weights -> 2 MFMAs/tile/rt.
template <int FI, int FO, int LBASE, bool EXTRACT>
__device__ __forceinline__ void layer_mfma(
    const _Float16* __restrict__ packd, const float* __restrict__ bld,
    int m, int q, int lane, float* __restrict__ bw,  // [4][16*36]
    const half8 (*A)[4], half8 (*O)[4]) {
  constexpr int KT = FI / 32, NT = FO / 16;
#pragma unroll
  for (int nt = 0; nt < NT; ++nt) {
    const float bias = bld[nt * 16 + m];
    f32x4 acc[4];
#pragma unroll
    for (int rt = 0; rt < 4; ++rt) acc[rt] = {bias, bias, bias, bias};
#pragma unroll
    for (int kt = 0; kt < KT; ++kt) {
      const _Float16* tb = packd + (size_t)(LBASE + nt * KT + kt) * TILE_HALVES;
      const half8 Bh = *(const half8*)(tb + lane * 8);
      const half8 Bl = *(const half8*)(tb + 512 + lane * 8);
#pragma unroll
      for (int rt = 0; rt < 4; ++rt) {
        acc[rt] = __builtin_amdgcn_mfma_f32_16x16x32_f16(A[rt][kt], Bh, acc[rt], 0, 0, 0);
        acc[rt] = __builtin_amdgcn_mfma_f32_16x16x32_f16(A[rt][kt], Bl, acc[rt], 0, 0, 0);
      }
    }
    const int hcol = (nt & 1) * 16 + m;
#pragma unroll
    for (int rt = 0; rt < 4; ++rt)
#pragma unroll
      for (int r = 0; r < 4; ++r)
        bw[rt * 576 + (q * 4 + r) * 36 + hcol] = fmaxf(acc[rt][r], 0.0f);  // ReLU
    if (EXTRACT && (nt & 1)) {  // 32-col pair complete -> next A-frag ktn
      const int ktn = nt >> 1;
#pragma unroll
      for (int rt = 0; rt < 4; ++rt) {
        const float* p = &bw[rt * 576 + m * 36 + q * 8];  // 16B-aligned
        const f32x4 v0 = *(const f32x4*)p;
        const f32x4 v1 = *(const f32x4*)(p + 4);
        float h[8];
#pragma unroll
        for (int j = 0; j < 4; ++j) { h[j] = v0[j]; h[4 + j] = v1[j]; }
        cvt8(h, O[rt][ktn]);
      }
    }
  }
}

__global__ __launch_bounds__(256, 1) void mlp_mfma(
    const float* __restrict__ x,
    const float* __restrict__ W0, const float* __restrict__ b0,
    const float* __restrict__ b1, const float* __restrict__ b2,
    const float* __restrict__ b3, const float* __restrict__ b4,
    const float* __restrict__ b5,
    const float* __restrict__ W6, const float* __restrict__ b6,
    const _Float16* __restrict__ pack, float* __restrict__ out) {
  const int lane = threadIdx.x & 63;
  const int wave = threadIdx.x >> 6;
  const int m = lane & 15, q = lane >> 4;
  const int d = blockIdx.x;
  const int row0 = blockIdx.y * 256 + wave * 64;  // 64 rows per wave

  __shared__ __align__(16) float buf[4][4 * 576];  // per-wave, no barriers
  float* bw = buf[wave];
  const _Float16* packd = pack + (size_t)d * NTILES * TILE_HALVES;

  half8 A0[4][4], A1[4][4];

  // L0: 1 -> 32 in VALU (wave-uniform scalar weights) -> L1 A-frags.
#pragma unroll
  for (int rt = 0; rt < 4; ++rt) {
    const float xv = x[(size_t)(row0 + rt * 16 + m) * DIM + d];
    float h[8];
#pragma unroll
    for (int j = 0; j < 8; ++j)
      h[j] = fmaxf(fmaf(xv, W0[d * 32 + q * 8 + j], b0[d * 32 + q * 8 + j]), 0.0f);
    cvt8(h, A0[rt][0]);
  }

  layer_mfma<32, 64, 0, true>(packd, b1 + d * 64, m, q, lane, bw, A0, A1);
  layer_mfma<64, 128, 4, true>(packd, b2 + d * 128, m, q, lane, bw, A1, A0);
  layer_mfma<128, 64, 20, true>(packd, b3 + d * 64, m, q, lane, bw, A0, A1);
  layer_mfma<64, 32, 36, true>(packd, b4 + d * 32, m, q, lane, bw, A1, A0);
  layer_mfma<32, 16, 40, false>(packd, b5 + d * 16, m, q, lane, bw, A0, A1);

  // L6: 16 -> 1 from LDS; shuffle-reduce 16 cols; atomicAdd over d.
  {
    const float w6 = W6[d * 16 + m];
    const float bias6 = b6[d];
#pragma unroll
    for (int rt = 0; rt < 4; ++rt) {
#pragma unroll
      for (int r = 0; r < 4; ++r) {
        float v = bw[rt * 576 + (q * 4 + r) * 36 + m] * w6;
        v += __shfl_xor(v, 1);
        v += __shfl_xor(v, 2);
        v += __shfl_xor(v, 4);
        v += __shfl_xor(v, 8);
        if (m == 0)
          atomicAdd(&out[row0 + rt * 16 + q * 4 + r], v + bias6);
      }
    }
  }
}

extern "C" void kernel_launch(void* const* d_in, const int* in_sizes, int n_in,
                              void* d_out, int out_size, void* d_ws, size_t ws_size,
                              hipStream_t stream) {
  const float* x = (const float*)d_in[0];
  const float* W[7];
  const float* B[7];
  for (int l = 0; l < 7; ++l) {
    W[l] = (const float*)d_in[1 + 2 * l];
    B[l] = (const float*)d_in[2 + 2 * l];
  }
  _Float16* pack = (_Float16*)d_ws;  // 21 MB packed weights

  // Harness poisons d_out to 0xAA before each launch; we accumulate with
  // atomics, so zero it first (hipMemsetAsync is graph-capturable).
  hipMemsetAsync(d_out, 0, (size_t)out_size * sizeof(float), stream);

  prep_kernel<<<dim3(DIM, 5), dim3(256), 0, stream>>>(W[1], W[2], W[3], W[4],
                                                      W[5], pack);

  mlp_mfma<<<dim3(DIM, BATCH / 256), dim3(256), 0, stream>>>(
      x, W[0], B[0], B[1], B[2], B[3], B[4], B[5], W[6], B[6], pack,
      (float*)d_out);
}

// Round 8
// 158.740 us; speedup vs baseline: 1.2696x; 1.2696x over previous
//
#include <hip/hip_runtime.h>

#define BATCH 2048
#define DIM   256

typedef _Float16 half8 __attribute__((ext_vector_type(8)));  // 8 x f16 (4 VGPR)
typedef _Float16 half4 __attribute__((ext_vector_type(4)));
typedef __attribute__((ext_vector_type(4))) float f32x4;

// Packed-weight tile table (layers 1..5):
// (FI,FO): (32,64) (64,128) (128,64) (64,32) (32,16)
// KT=FI/32, NT=FO/16, tiles=KT*NT: 4, 16, 16, 4, 1 -> bases 0,4,20,36,40
#define NTILES 41
#define TILE_HALVES 1024   // 64 lanes * 8 f16 * (hi+lo) = 2 KB
#define PACK_OFF_BYTES (BATCH * DIM * 4)   // partial buffer first (2 MB)

// ---- prep: gather W into B-frag order, split f16 hi/lo. One block per
// (d, layer) -> 1280 independent blocks, no LDS, no barriers. ----
template <int FI, int FO, int BASE>
__device__ __forceinline__ void prep_layer(const float* __restrict__ W, int d,
                                           int t, _Float16* __restrict__ pack) {
  constexpr int KT = FI / 32, NT = FO / 16, T = KT * NT;
  const float* Wd = W + (size_t)d * FI * FO;
  for (int job = t; job < T * 64; job += 256) {
    const int tile = job >> 6, lane = job & 63;
    const int m = lane & 15, q = lane >> 4;
    const int nt = tile / KT, kt = tile % KT;   // matches main's nt*KT+kt
    const float* Wp = Wd + (size_t)(kt * 32 + q * 8) * FO + nt * 16 + m;
    half8 hi, lo;
#pragma unroll
    for (int j = 0; j < 8; ++j) {
      const float w = Wp[(size_t)j * FO];
      const _Float16 h = (_Float16)w;
      hi[j] = h;
      lo[j] = (_Float16)(w - (float)h);
    }
    _Float16* base = pack + (size_t)(d * NTILES + BASE + tile) * TILE_HALVES;
    *(half8*)(base + lane * 8) = hi;
    *(half8*)(base + 512 + lane * 8) = lo;
  }
}

__global__ __launch_bounds__(256) void prep_kernel(
    const float* __restrict__ W1, const float* __restrict__ W2,
    const float* __restrict__ W3, const float* __restrict__ W4,
    const float* __restrict__ W5, _Float16* __restrict__ pack) {
  const int d = blockIdx.x, t = threadIdx.x;
  switch (blockIdx.y) {
    case 0: prep_layer<32, 64, 0>(W1, d, t, pack); break;
    case 1: prep_layer<64, 128, 4>(W2, d, t, pack); break;
    case 2: prep_layer<128, 64, 20>(W3, d, t, pack); break;
    case 3: prep_layer<64, 32, 36>(W4, d, t, pack); break;
    default: prep_layer<32, 16, 40>(W5, d, t, pack); break;
  }
}

// ---- one MFMA layer for RT=4 row-tiles (M=64) owned by one wave ----
// A = f16 activations (hi only), B = f16 hi+lo weights -> 2 MFMAs/tile/rt.
// Activations round-trip through a per-wave f16 LDS buffer (stride 36 halves:
// keeps block LDS at 18432 B -> 8 blocks/CU, extract = 2x ds_read_b64).
template <int FI, int FO, int LBASE, bool EXTRACT>
__device__ __forceinline__ void layer_mfma(
    const _Float16* __restrict__ packd, const float* __restrict__ bld,
    int m, int q, int lane, _Float16* __restrict__ bw,  // [4][16*36] halves
    const half8 (*A)[4], half8 (*O)[4]) {
  constexpr int KT = FI / 32, NT = FO / 16;
#pragma unroll
  for (int nt = 0; nt < NT; ++nt) {
    const float bias = bld[nt * 16 + m];
    f32x4 acc[4];
#pragma unroll
    for (int rt = 0; rt < 4; ++rt) acc[rt] = {bias, bias, bias, bias};
#pragma unroll
    for (int kt = 0; kt < KT; ++kt) {
      const _Float16* tb = packd + (size_t)(LBASE + nt * KT + kt) * TILE_HALVES;
      const half8 Bh = *(const half8*)(tb + lane * 8);
      const half8 Bl = *(const half8*)(tb + 512 + lane * 8);
#pragma unroll
      for (int rt = 0; rt < 4; ++rt) {
        acc[rt] = __builtin_amdgcn_mfma_f32_16x16x32_f16(A[rt][kt], Bh, acc[rt], 0, 0, 0);
        acc[rt] = __builtin_amdgcn_mfma_f32_16x16x32_f16(A[rt][kt], Bl, acc[rt], 0, 0, 0);
      }
    }
    const int hcol = (nt & 1) * 16 + m;
#pragma unroll
    for (int rt = 0; rt < 4; ++rt)
#pragma unroll
      for (int r = 0; r < 4; ++r)
        bw[rt * 576 + (q * 4 + r) * 36 + hcol] =
            (_Float16)fmaxf(acc[rt][r], 0.0f);  // ReLU + cvt on write
    if (EXTRACT && (nt & 1)) {  // 32-col pair complete -> next A-frag ktn
      const int ktn = nt >> 1;
#pragma unroll
      for (int rt = 0; rt < 4; ++rt) {
        const _Float16* p = &bw[rt * 576 + m * 36 + q * 8];  // 8-B aligned
        const half4 v0 = *(const half4*)p;
        const half4 v1 = *(const half4*)(p + 4);
        half8 o;
#pragma unroll
        for (int j = 0; j < 4; ++j) { o[j] = v0[j]; o[4 + j] = v1[j]; }
        O[rt][ktn] = o;
      }
    }
  }
}

__global__ __launch_bounds__(256, 1) void mlp_mfma(
    const float* __restrict__ x,
    const float* __restrict__ W0, const float* __restrict__ b0,
    const float* __restrict__ b1, const float* __restrict__ b2,
    const float* __restrict__ b3, const float* __restrict__ b4,
    const float* __restrict__ b5,
    const float* __restrict__ W6, const float* __restrict__ b6,
    const _Float16* __restrict__ pack, float* __restrict__ partial) {
  const int lane = threadIdx.x & 63;
  const int wave = threadIdx.x >> 6;
  const int m = lane & 15, q = lane >> 4;
  const int d = blockIdx.x;
  const int row0 = blockIdx.y * 256 + wave * 64;  // 64 rows per wave

  __shared__ __align__(16) _Float16 buf[4][4 * 576];  // per-wave, no barriers
  _Float16* bw = buf[wave];
  const _Float16* packd = pack + (size_t)d * NTILES * TILE_HALVES;

  half8 A0[4][4], A1[4][4];

  // L0: 1 -> 32 in VALU (wave-uniform scalar weights) -> L1 A-frags.
#pragma unroll
  for (int rt = 0; rt < 4; ++rt) {
    const float xv = x[(size_t)(row0 + rt * 16 + m) * DIM + d];
    half8 h;
#pragma unroll
    for (int j = 0; j < 8; ++j)
      h[j] = (_Float16)fmaxf(
          fmaf(xv, W0[d * 32 + q * 8 + j], b0[d * 32 + q * 8 + j]), 0.0f);
    A0[rt][0] = h;
  }

  layer_mfma<32, 64, 0, true>(packd, b1 + d * 64, m, q, lane, bw, A0, A1);
  layer_mfma<64, 128, 4, true>(packd, b2 + d * 128, m, q, lane, bw, A1, A0);
  layer_mfma<128, 64, 20, true>(packd, b3 + d * 64, m, q, lane, bw, A0, A1);
  layer_mfma<64, 32, 36, true>(packd, b4 + d * 32, m, q, lane, bw, A1, A0);
  layer_mfma<32, 16, 40, false>(packd, b5 + d * 16, m, q, lane, bw, A0, A1);

  // L6: 16 -> 1 from LDS; shuffle-reduce 16 cols.
  {
    const float w6 = W6[d * 16 + m];
    const float bias6 = b6[d];
#pragma unroll
    for (int rt = 0; rt < 4; ++rt) {
#pragma unroll
      for (int r = 0; r < 4; ++r) {
        float v = (float)bw[rt * 576 + (q * 4 + r) * 36 + m] * w6;
        v += __shfl_xor(v, 1);
        v += __shfl_xor(v, 2);
        v += __shfl_xor(v, 4);
        v += __shfl_xor(v, 8);
        if (m == 0)
          partial[(size_t)d * BATCH + row0 + rt * 16 + q * 4 + r] = v + bias6;
      }
    }
  }
}

__global__ __launch_bounds__(256) void reduce_kernel(
    const float* __restrict__ partial, float* __restrict__ out) {
  const int b = blockIdx.x * blockDim.x + threadIdx.x;
  float s = 0.0f;
#pragma unroll 8
  for (int d = 0; d < DIM; ++d) s += partial[(size_t)d * BATCH + b];
  out[b] = s;
}

extern "C" void kernel_launch(void* const* d_in, const int* in_sizes, int n_in,
                              void* d_out, int out_size, void* d_ws, size_t ws_size,
                              hipStream_t stream) {
  const float* x = (const float*)d_in[0];
  const float* W[7];
  const float* B[7];
  for (int l = 0; l < 7; ++l) {
    W[l] = (const float*)d_in[1 + 2 * l];
    B[l] = (const float*)d_in[2 + 2 * l];
  }
  float* partial = (float*)d_ws;                               // 2 MB
  _Float16* pack = (_Float16*)((char*)d_ws + PACK_OFF_BYTES);  // 21 MB

  prep_kernel<<<dim3(DIM, 5), dim3(256), 0, stream>>>(W[1], W[2], W[3], W[4],
                                                      W[5], pack);

  mlp_mfma<<<dim3(DIM, BATCH / 256), dim3(256), 0, stream>>>(
      x, W[0], B[0], B[1], B[2], B[3], B[4], B[5], W[6], B[6], pack, partial);

  reduce_kernel<<<dim3(BATCH / 256), dim3(256), 0, stream>>>(partial,
                                                             (float*)d_out);
}

// Round 9
// 157.324 us; speedup vs baseline: 1.2810x; 1.0090x over previous
//
#include <hip/hip_runtime.h>

#define BATCH 2048
#define DIM   256
#define WAVES 8   // 512 threads/block

typedef _Float16 half8 __attribute__((ext_vector_type(8)));  // 8 x f16 (4 VGPR)
typedef _Float16 half4 __attribute__((ext_vector_type(4)));
typedef __attribute__((ext_vector_type(4))) float f32x4;

// Packed-weight tile table (layers 1..5):
// (FI,FO): (32,64) (64,128) (128,64) (64,32) (32,16)
// KT=FI/32, NT=FO/16, tiles=KT*NT: 4, 16, 16, 4, 1 -> bases 0,4,20,36,40
#define NTILES 41
#define TILE_HALVES 1024   // 64 lanes * 8 f16 * (hi+lo) = 2 KB

// ---- one MFMA layer for RT=4 row-tiles (M=64) owned by one wave ----
// A = f16 activations (hi only), B = f16 hi+lo weights in LDS -> 2 MFMA/tile/rt.
// Activations round-trip through a per-wave f16 LDS buffer (stride 36 halves).
template <int FI, int FO, int LBASE, bool EXTRACT>
__device__ __forceinline__ void layer_mfma(
    const _Float16* __restrict__ packs,   // LDS: 41 tiles * 1024 halves
    const float* __restrict__ bld,
    int m, int q, int lane, _Float16* __restrict__ bw,  // LDS [4][16*36]
    const half8 (*A)[4], half8 (*O)[4]) {
  constexpr int KT = FI / 32, NT = FO / 16;
#pragma unroll
  for (int nt = 0; nt < NT; ++nt) {
    const float bias = bld[nt * 16 + m];
    f32x4 acc[4];
#pragma unroll
    for (int rt = 0; rt < 4; ++rt) acc[rt] = {bias, bias, bias, bias};
#pragma unroll
    for (int kt = 0; kt < KT; ++kt) {
      const _Float16* tb = packs + (size_t)(LBASE + nt * KT + kt) * TILE_HALVES;
      const half8 Bh = *(const half8*)(tb + lane * 8);
      const half8 Bl = *(const half8*)(tb + 512 + lane * 8);
#pragma unroll
      for (int rt = 0; rt < 4; ++rt) {
        acc[rt] = __builtin_amdgcn_mfma_f32_16x16x32_f16(A[rt][kt], Bh, acc[rt], 0, 0, 0);
        acc[rt] = __builtin_amdgcn_mfma_f32_16x16x32_f16(A[rt][kt], Bl, acc[rt], 0, 0, 0);
      }
    }
    const int hcol = (nt & 1) * 16 + m;
#pragma unroll
    for (int rt = 0; rt < 4; ++rt)
#pragma unroll
      for (int r = 0; r < 4; ++r)
        bw[rt * 576 + (q * 4 + r) * 36 + hcol] =
            (_Float16)fmaxf(acc[rt][r], 0.0f);  // ReLU + cvt on write
    if (EXTRACT && (nt & 1)) {  // 32-col pair complete -> next A-frag ktn
      const int ktn = nt >> 1;
#pragma unroll
      for (int rt = 0; rt < 4; ++rt) {
        const _Float16* p = &bw[rt * 576 + m * 36 + q * 8];  // 8-B aligned
        const half4 v0 = *(const half4*)p;
        const half4 v1 = *(const half4*)(p + 4);
        half8 o;
#pragma unroll
        for (int j = 0; j < 4; ++j) { o[j] = v0[j]; o[4 + j] = v1[j]; }
        O[rt][ktn] = o;
      }
    }
  }
}

// ---- fused kernel: one block per d. Phase 1: pack W[d] into LDS (f16 hi/lo,
// B-frag order). Phase 2: 4 row-group iterations (8 waves x 64 rows) of MFMA.
__global__ __launch_bounds__(512, 2) void mlp_fused(
    const float* __restrict__ x,
    const float* __restrict__ W0, const float* __restrict__ b0,
    const float* __restrict__ W1, const float* __restrict__ b1,
    const float* __restrict__ W2, const float* __restrict__ b2,
    const float* __restrict__ W3, const float* __restrict__ b3,
    const float* __restrict__ W4, const float* __restrict__ b4,
    const float* __restrict__ W5, const float* __restrict__ b5,
    const float* __restrict__ W6, const float* __restrict__ b6,
    float* __restrict__ partial) {
  const int t = threadIdx.x;
  const int lane = t & 63;
  const int wave = t >> 6;
  const int m = lane & 15, q = lane >> 4;
  const int d = blockIdx.x;

  __shared__ __align__(16) _Float16 packs[NTILES * TILE_HALVES];  // 84 KB
  __shared__ __align__(16) _Float16 act[WAVES][4 * 576];          // 36 KB

  // ---- phase 1: gather W1..W5[d] into LDS pack (frag order, f16 hi/lo) ----
  for (int job = t; job < NTILES * 64; job += 512) {
    const int tile = job >> 6, jl = job & 63;
    const int jm = jl & 15, jq = jl >> 4;
    const float* W; int FI, FO, lt;
    if (tile < 4)       { W = W1; FI = 32;  FO = 64;  lt = tile; }
    else if (tile < 20) { W = W2; FI = 64;  FO = 128; lt = tile - 4; }
    else if (tile < 36) { W = W3; FI = 128; FO = 64;  lt = tile - 20; }
    else if (tile < 40) { W = W4; FI = 64;  FO = 32;  lt = tile - 36; }
    else                { W = W5; FI = 32;  FO = 16;  lt = 0; }
    const int KT = FI >> 5;
    const int nt = lt / KT, kt = lt - nt * KT;   // matches layer_mfma order
    const float* Wp = W + (size_t)d * FI * FO +
                      (size_t)(kt * 32 + jq * 8) * FO + nt * 16 + jm;
    half8 hi, lo;
#pragma unroll
    for (int j = 0; j < 8; ++j) {
      const float w = Wp[(size_t)j * FO];
      const _Float16 h = (_Float16)w;
      hi[j] = h;
      lo[j] = (_Float16)(w - (float)h);
    }
    _Float16* base = packs + (size_t)tile * TILE_HALVES;
    *(half8*)(base + jl * 8) = hi;
    *(half8*)(base + 512 + jl * 8) = lo;
  }

  // Hoist wave-uniform L0/L6 params while the pack settles.
  float w0r[8], b0r[8];
#pragma unroll
  for (int j = 0; j < 8; ++j) {
    w0r[j] = W0[d * 32 + q * 8 + j];
    b0r[j] = b0[d * 32 + q * 8 + j];
  }
  const float w6 = W6[d * 16 + m];
  const float bias6 = b6[d];

  __syncthreads();   // pack ready; the ONLY barrier

  _Float16* bw = act[wave];
  half8 A0[4][4], A1[4][4];

  // ---- phase 2: 4 iterations x (8 waves * 64 rows) = 2048 rows ----
  for (int it = 0; it < 4; ++it) {
    const int row0 = it * 512 + wave * 64;

    // L0: 1 -> 32 in VALU -> L1 A-frags.
#pragma unroll
    for (int rt = 0; rt < 4; ++rt) {
      const float xv = x[(size_t)(row0 + rt * 16 + m) * DIM + d];
      half8 h;
#pragma unroll
      for (int j = 0; j < 8; ++j)
        h[j] = (_Float16)fmaxf(fmaf(xv, w0r[j], b0r[j]), 0.0f);
      A0[rt][0] = h;
    }

    layer_mfma<32, 64, 0, true>(packs, b1 + d * 64, m, q, lane, bw, A0, A1);
    layer_mfma<64, 128, 4, true>(packs, b2 + d * 128, m, q, lane, bw, A1, A0);
    layer_mfma<128, 64, 20, true>(packs, b3 + d * 64, m, q, lane, bw, A0, A1);
    layer_mfma<64, 32, 36, true>(packs, b4 + d * 32, m, q, lane, bw, A1, A0);
    layer_mfma<32, 16, 40, false>(packs, b5 + d * 16, m, q, lane, bw, A0, A1);

    // L6: 16 -> 1 from LDS; shuffle-reduce 16 cols.
#pragma unroll
    for (int rt = 0; rt < 4; ++rt) {
#pragma unroll
      for (int r = 0; r < 4; ++r) {
        float v = (float)bw[rt * 576 + (q * 4 + r) * 36 + m] * w6;
        v += __shfl_xor(v, 1);
        v += __shfl_xor(v, 2);
        v += __shfl_xor(v, 4);
        v += __shfl_xor(v, 8);
        if (m == 0)
          partial[(size_t)d * BATCH + row0 + rt * 16 + q * 4 + r] = v + bias6;
      }
    }
  }
}

__global__ __launch_bounds__(256) void reduce_kernel(
    const float* __restrict__ partial, float* __restrict__ out) {
  const int b = blockIdx.x * blockDim.x + threadIdx.x;
  float s = 0.0f;
#pragma unroll 8
  for (int d = 0; d < DIM; ++d) s += partial[(size_t)d * BATCH + b];
  out[b] = s;
}

extern "C" void kernel_launch(void* const* d_in, const int* in_sizes, int n_in,
                              void* d_out, int out_size, void* d_ws, size_t ws_size,
                              hipStream_t stream) {
  const float* x = (const float*)d_in[0];
  const float* W[7];
  const float* B[7];
  for (int l = 0; l < 7; ++l) {
    W[l] = (const float*)d_in[1 + 2 * l];
    B[l] = (const float*)d_in[2 + 2 * l];
  }
  float* partial = (float*)d_ws;  // 2 MB only (pack now lives in LDS)

  mlp_fused<<<dim3(DIM), dim3(512), 0, stream>>>(
      x, W[0], B[0], W[1], B[1], W[2], B[2], W[3], B[3], W[4], B[4], W[5], B[5],
      W[6], B[6], partial);

  reduce_kernel<<<dim3(BATCH / 256), dim3(256), 0, stream>>>(partial,
                                                             (float*)d_out);
}